// Round 9
// baseline (202.933 us; speedup 1.0000x reference)
//
#include <hip/hip_runtime.h>
#include <hip/hip_bf16.h>
#include <math.h>

#define B_ 64
#define C_ 256
#define H_ 16
#define W_ 16
#define NEG_ 16
#define PRED_ 5
#define EPS_ 1e-11f
#define LDW 18    // logit tile row stride (floats)
#define CTXW 264  // ctx row stride in shorts (528 B): bank = l15*4+... -> 2-way, free

typedef __attribute__((ext_vector_type(8))) short bf16x8;
typedef __attribute__((ext_vector_type(4))) float f32x4;

static __device__ __forceinline__ unsigned short f2bu(float f) {
  __hip_bfloat16 h = __float2bfloat16(f);
  return *(unsigned short*)&h;
}

// ws layout (bytes):
//   Zp bf16 [16384][256] : 0         (8388608)  rows q*64+b; rows<2048 (h<2) unused
//   Cb bf16 [16384][256] : 8388608   (8388608)  rows>=14336 (h>=14) unused
//   Wb bf16 [5][256][256]: 16777216  (655360)
//   Yb bf16 [5][14336][256]: 17432576 (36700160) rows>=M_k unused per k
//   Lk f32  [5][14336]   : 54132736  (286720)  tails [Mk,14336) NEVER read (no memset)
// Purity: every read is of data written earlier in this launch; total sums
// only rows [0,Mk) per k, finalize_pl only touches valid rows.

// ---- transpose+cast: in[p=b*256+i][q=h*16+w] -> out[q*64+b][i] (bf16) ----
__global__ __launch_bounds__(256) void transpose_zc(
    const float* __restrict__ z, const float* __restrict__ c,
    unsigned short* __restrict__ Zp, unsigned short* __restrict__ Cb) {
  __shared__ float tile[32][33];
  const float* in = blockIdx.z ? c : z;
  unsigned short* out = blockIdx.z ? Cb : Zp;
  int p0 = blockIdx.x * 32;                          // full [0,16384)
  int q0 = blockIdx.y * 32 + (blockIdx.z ? 0 : 32);  // z:[32,256) c:[0,224)
  int tx = threadIdx.x, ty = threadIdx.y;  // (32,8)
#pragma unroll
  for (int r = 0; r < 32; r += 8)
    tile[ty + r][tx] = in[(size_t)(p0 + ty + r) * 256 + q0 + tx];
  __syncthreads();
#pragma unroll
  for (int r = 0; r < 32; r += 8)
    out[(size_t)(q0 + ty + r) * 16384 + p0 + tx] = f2bu(tile[tx][ty + r]);
}

// ---- cast Wk (5*256*256 fp32) -> bf16 ----
__global__ __launch_bounds__(256) void cast_w(
    const float* __restrict__ Wk, unsigned short* __restrict__ Wb) {
  int i = blockIdx.x * 256 + threadIdx.x;
  float4 v = ((const float4*)Wk)[i];
  ushort4 o;
  o.x = f2bu(v.x); o.y = f2bu(v.y); o.z = f2bu(v.z); o.w = f2bu(v.w);
  ((ushort4*)Wb)[i] = o;
}

// ---- batched MFMA GEMM, register-double-buffered K loop ----
__global__ __launch_bounds__(256) void gemm_all(
    const unsigned short* __restrict__ Zp, const unsigned short* __restrict__ Wb,
    unsigned short* __restrict__ Yb) {
  const int kk = blockIdx.z;          // k = kk+1, off = kk+2
  const int Mk = (14 - kk) * 1024;
  const int m0b = blockIdx.y * 128;
  if (m0b >= Mk) return;
  const unsigned short* A = Zp + (size_t)(kk + 2) * 1024 * 256;
  const unsigned short* Wm = Wb + (size_t)kk * 65536;
  unsigned short* Y = Yb + (size_t)kk * 14336 * 256;
  const int t = threadIdx.x;
  const int wid = t >> 6, lane = t & 63;
  const int wm = wid >> 1, wn = wid & 1;
  const int l15 = lane & 15, quad = lane >> 4;
  const int m0 = m0b + wm * 64;
  const int n0 = blockIdx.x * 128 + wn * 64;
  const unsigned short* a0 = A + (size_t)(m0 + l15) * 256 + quad * 8;
  const unsigned short* b0 = Wm + (size_t)(n0 + l15) * 256 + quad * 8;
  f32x4 acc[4][4] = {};
  bf16x8 ac[4], bc[4], an[4], bn[4];
#pragma unroll
  for (int tm = 0; tm < 4; ++tm) ac[tm] = *(const bf16x8*)(a0 + tm * 16 * 256);
#pragma unroll
  for (int tn = 0; tn < 4; ++tn) bc[tn] = *(const bf16x8*)(b0 + tn * 16 * 256);
#pragma unroll
  for (int kb = 0; kb < 8; ++kb) {
    if (kb < 7) {
      const int k1 = (kb + 1) * 32;
#pragma unroll
      for (int tm = 0; tm < 4; ++tm) an[tm] = *(const bf16x8*)(a0 + tm * 16 * 256 + k1);
#pragma unroll
      for (int tn = 0; tn < 4; ++tn) bn[tn] = *(const bf16x8*)(b0 + tn * 16 * 256 + k1);
    }
#pragma unroll
    for (int tm = 0; tm < 4; ++tm)
#pragma unroll
      for (int tn = 0; tn < 4; ++tn)
        acc[tm][tn] = __builtin_amdgcn_mfma_f32_16x16x32_bf16(ac[tm], bc[tn], acc[tm][tn], 0, 0, 0);
#pragma unroll
    for (int tm = 0; tm < 4; ++tm) ac[tm] = an[tm];
#pragma unroll
    for (int tn = 0; tn < 4; ++tn) bc[tn] = bn[tn];
  }
#pragma unroll
  for (int tm = 0; tm < 4; ++tm)
#pragma unroll
    for (int tn = 0; tn < 4; ++tn)
#pragma unroll
      for (int r = 0; r < 4; ++r)
        Y[(size_t)(m0 + tm * 16 + quad * 4 + r) * 256 + n0 + tn * 16 + l15] =
            f2bu(acc[tm][tn][r]);
}

// ---- fused scoring: one block (8 waves, 512 thr) per 16-row group ----
// ctx staged once in padded LDS; af[8] resident per wave; 17 chains split
// 3/2/2/2/2/2/2/2 across 8 waves; gathered B fragments double-buffered.
__global__ __launch_bounds__(512) void score_all(
    const unsigned short* __restrict__ Yb, const unsigned short* __restrict__ Cb,
    const int* __restrict__ r1, const int* __restrict__ r2,
    const int* __restrict__ r3, const int* __restrict__ r4,
    const int* __restrict__ r5, float* __restrict__ Lk) {
  __shared__ unsigned short ctx[16 * CTXW];   // 8448 B, padded rows
  __shared__ float L[16 * LDW];
  const int wv = threadIdx.x >> 6, lane = threadIdx.x & 63;
  const int gid = blockIdx.x;                // 0..3839
  int kk, base;
  if (gid < 896)       { kk = 0; base = 0; }
  else if (gid < 1728) { kk = 1; base = 896; }
  else if (gid < 2496) { kk = 2; base = 1728; }
  else if (gid < 3200) { kk = 3; base = 2496; }
  else                 { kk = 4; base = 3200; }
  const int Mk = (14 - kk) * 1024;
  const int m0 = (gid - base) * 16;
  const int* ridx = kk == 0 ? r1 : kk == 1 ? r2 : kk == 2 ? r3 : kk == 3 ? r4 : r5;
  const unsigned short* Y = Yb + (size_t)kk * 14336 * 256;
  const int l15 = lane & 15, quad = lane >> 4;

  // stage ctx rows m0..m0+15 into padded LDS (512 thr x uint4 = 4096 shorts)
  {
    int r = threadIdx.x >> 5, s = threadIdx.x & 31;
    *(uint4*)(ctx + r * CTXW + s * 8) =
        ((const uint4*)(Cb + (size_t)(m0 + r) * 256))[s];
  }
  __syncthreads();

  // A fragments from LDS, once, resident across all chains (2-way banks: free)
  bf16x8 af[8];
#pragma unroll
  for (int tv = 0; tv < 8; ++tv)
    af[tv] = *(const bf16x8*)(ctx + l15 * CTXW + quad * 8 + tv * 32);

  // chain c: 0 = main (B rows m0..m0+15), c>=1 = neg i=c-1 (gathered rows)
  const int c0 = (wv == 0) ? 0 : (2 * wv + 1);
  const int nc = (wv == 0) ? 3 : 2;

  const unsigned short* bp;
  {
    const int c = c0;
    if (c == 0) bp = Y + (size_t)(m0 + l15) * 256 + quad * 8;
    else {
      int idx = ridx[(m0 + (c - 1)) * NEG_ + l15];
      idx = idx < 0 ? 0 : (idx >= Mk ? Mk - 1 : idx);
      bp = Y + (size_t)idx * 256 + quad * 8;
    }
  }
  bf16x8 bcur[8], bnxt[8];
#pragma unroll
  for (int tv = 0; tv < 8; ++tv) bcur[tv] = *(const bf16x8*)(bp + tv * 32);

  for (int j = 0; j < nc; ++j) {
    if (j + 1 < nc) {
      const int c = c0 + j + 1;    // >= 1 always (main is first)
      int idx = ridx[(m0 + (c - 1)) * NEG_ + l15];
      idx = idx < 0 ? 0 : (idx >= Mk ? Mk - 1 : idx);
      const unsigned short* np = Y + (size_t)idx * 256 + quad * 8;
#pragma unroll
      for (int tv = 0; tv < 8; ++tv) bnxt[tv] = *(const bf16x8*)(np + tv * 32);
    }
    f32x4 acc = {};
#pragma unroll
    for (int tv = 0; tv < 8; ++tv)
      acc = __builtin_amdgcn_mfma_f32_16x16x32_bf16(af[tv], bcur[tv], acc, 0, 0, 0);
    const int c = c0 + j;
    if (c == 0) {
#pragma unroll
      for (int r = 0; r < 4; ++r)
        if (l15 == quad * 4 + r) L[(quad * 4 + r) * LDW] = acc[r];
    } else {
      const int i = c - 1;
      if (quad == (i >> 2)) L[i * LDW + 1 + l15] = acc[i & 3];
    }
#pragma unroll
    for (int tv = 0; tv < 8; ++tv) bcur[tv] = bnxt[tv];
  }
  __syncthreads();
  if (threadIdx.x < 16) {
    const int m = m0 + threadIdx.x;
    float mainv = L[threadIdx.x * LDW];
    float mx = mainv;
    float nv[NEG_];
#pragma unroll
    for (int n = 0; n < NEG_; ++n) {
      nv[n] = L[threadIdx.x * LDW + 1 + n];
      mx = fmaxf(mx, nv[n]);
    }
    float num = __expf(mainv - mx);
    float se = num;
#pragma unroll
    for (int n = 0; n < NEG_; ++n) se += __expf(nv[n] - mx);
    Lk[kk * 14336 + m] = -logf(num / se + EPS_);
  }
}

// ---- total loss: one block, sums only valid rows [0,Mk) per k ----
__global__ __launch_bounds__(1024) void total_all(
    const float* __restrict__ Lk, float* __restrict__ out) {
  __shared__ float red[1024];
  const int t = threadIdx.x;
  float local = 0.f;
#pragma unroll
  for (int kk = 0; kk < PRED_; ++kk) {
    const int Mk = (14 - kk) * 1024;
    const float scale = 1.0f / (5120.0f * (float)(14 - kk));
    for (int e = t; e < Mk; e += 1024)
      local += Lk[kk * 14336 + e] * scale;
  }
  red[t] = local;
  __syncthreads();
  for (int s = 512; s; s >>= 1) {
    if (t < s) red[t] += red[t + s];
    __syncthreads();
  }
  if (t == 0) out[0] = red[0];
}

// ---- patchwise loss + counts (pure gather, each out element written once) ----
__global__ __launch_bounds__(256) void finalize_pl(
    const float* __restrict__ Lk, float* __restrict__ out) {
  int idx = blockIdx.x * 256 + threadIdx.x;   // b*256 + h*16 + w
  int b = idx >> 8, h = (idx >> 4) & 15, w = idx & 15;
  float v = 0.f;
#pragma unroll
  for (int kk = 0; kk < PRED_; ++kk) {
    int off = kk + 2;
    if (h >= off)      v += Lk[kk * 14336 + ((h - off) * 16 + w) * 64 + b];
    if (h <= 15 - off) v += Lk[kk * 14336 + (h * 16 + w) * 64 + b];
  }
  out[1 + idx] = v;
  if (idx < 256) {
    int hh = idx >> 4;
    float cnt = 0.f;
#pragma unroll
    for (int off = 2; off <= 6; ++off)
      cnt += (hh >= off ? 1.f : 0.f) + (hh <= 15 - off ? 1.f : 0.f);
    out[1 + 16384 + idx] = cnt;
  }
}

extern "C" void kernel_launch(void* const* d_in, const int* in_sizes, int n_in,
                              void* d_out, int out_size, void* d_ws, size_t ws_size,
                              hipStream_t stream) {
  const float* z  = (const float*)d_in[0];
  const float* c  = (const float*)d_in[1];
  const float* Wk = (const float*)d_in[2];
  float* out = (float*)d_out;
  char* wsb = (char*)d_ws;
  unsigned short* Zp = (unsigned short*)(wsb);
  unsigned short* Cb = (unsigned short*)(wsb + 8388608);
  unsigned short* Wb = (unsigned short*)(wsb + 16777216);
  unsigned short* Yb = (unsigned short*)(wsb + 17432576);
  float*          Lk = (float*)(wsb + 54132736);

  transpose_zc<<<dim3(512, 7, 2), dim3(32, 8), 0, stream>>>(z, c, Zp, Cb);
  cast_w<<<320, 256, 0, stream>>>(Wk, Wb);
  gemm_all<<<dim3(2, 112, PRED_), 256, 0, stream>>>(Zp, Wb, Yb);
  score_all<<<3840, 512, 0, stream>>>(
      Yb, Cb, (const int*)d_in[3], (const int*)d_in[4], (const int*)d_in[5],
      (const int*)d_in[6], (const int*)d_in[7], Lk);
  finalize_pl<<<64, 256, 0, stream>>>(Lk, out);
  total_all<<<1, 1024, 0, stream>>>(Lk, out);
}